// Round 1
// baseline (131.918 us; speedup 1.0000x reference)
//
#include <hip/hip_runtime.h>
#include <hip/hip_bf16.h>
#include <stdint.h>

// Problem constants: B=4, N=4096, C=1024, H=16, d=64
#define SEQ_N   4096
#define CDIM    1024
#define HEADS   16
#define HDIM    64

typedef __attribute__((ext_vector_type(8))) short bf16x8;
typedef __attribute__((ext_vector_type(4))) float f32x4;

__device__ __forceinline__ void gload_lds16(const void* g, void* l) {
  auto* gp = reinterpret_cast<__attribute__((address_space(1))) uint32_t*>((uintptr_t)g);
  auto* lp = reinterpret_cast<__attribute__((address_space(3))) uint32_t*>((uintptr_t)l);
  __builtin_amdgcn_global_load_lds(gp, lp, 16, 0, 0);
}

// ---------------------------------------------------------------------------
// Kernel 1: per-token head-mix attention.
// For token (b,n): S[h][g] = sum_d x[h*64+d]*y[g*64+d] / 8; P = softmax_g(S);
// o[h][dd] = sum_g P[h][g]*y[g*64+dd].
// Written bf16 into A at [b*4096 + h*256 + n/16][ (n%16)*64 + dd ]
// (the torch transpose(1,2).reshape(B,N,C) layout, ready for the GEMM).
// One wave per token, 4 waves/block.
// ---------------------------------------------------------------------------
__global__ __launch_bounds__(256) void attn_kernel(
    const float* __restrict__ x, const float* __restrict__ y,
    __hip_bfloat16* __restrict__ A)
{
  __shared__ float xsT[4][HDIM * HEADS];    // [d][h]  (transposed: conflict-free dots)
  __shared__ float ysT[4][HDIM * HEADS];    // [d][g]
  __shared__ float ysr[4][CDIM];            // y row natural layout [g*64+dd]
  __shared__ float Ps [4][HEADS * HEADS];   // [h][g]

  const int wid  = threadIdx.x >> 6;
  const int lane = threadIdx.x & 63;
  const int tok  = blockIdx.x * 4 + wid;    // 0..16383
  const int b    = tok >> 12;
  const int n    = tok & 4095;

  const float* xr = x + (size_t)tok * CDIM;
  const float* yr = y + (size_t)tok * CDIM;

  // Load + transpose into LDS (float4 global loads, coalesced).
  #pragma unroll
  for (int i = 0; i < 4; ++i) {
    const int c = i * 256 + lane * 4;       // 0..1023, 4 at a time
    const float4 xv = *(const float4*)(xr + c);
    const float4 yv = *(const float4*)(yr + c);
    *(float4*)&ysr[wid][c] = yv;
    const int d0 = c & 63, h0 = c >> 6;     // c..c+3 share h0
    xsT[wid][(d0 + 0) * 16 + h0] = xv.x;
    xsT[wid][(d0 + 1) * 16 + h0] = xv.y;
    xsT[wid][(d0 + 2) * 16 + h0] = xv.z;
    xsT[wid][(d0 + 3) * 16 + h0] = xv.w;
    ysT[wid][(d0 + 0) * 16 + h0] = yv.x;
    ysT[wid][(d0 + 1) * 16 + h0] = yv.y;
    ysT[wid][(d0 + 2) * 16 + h0] = yv.z;
    ysT[wid][(d0 + 3) * 16 + h0] = yv.w;
  }
  __syncthreads();

  // Stage A: scores. Lane owns pairs (h = i*4 + lane/16, g = lane%16), i=0..3.
  const int g  = lane & 15;
  const int hq = lane >> 4;
  float S[4] = {0.f, 0.f, 0.f, 0.f};
  for (int dc = 0; dc < 4; ++dc) {
    float yv[16];
    #pragma unroll
    for (int j = 0; j < 16; ++j) yv[j] = ysT[wid][(dc * 16 + j) * 16 + g];
    #pragma unroll
    for (int i = 0; i < 4; ++i) {
      const int h = i * 4 + hq;
      float s = 0.f;
      #pragma unroll
      for (int j = 0; j < 16; ++j) s += xsT[wid][(dc * 16 + j) * 16 + h] * yv[j];
      S[i] += s;
    }
  }

  // Stage B: softmax over g. Each row lives in one contiguous 16-lane group.
  #pragma unroll
  for (int i = 0; i < 4; ++i) {
    const float v = S[i] * 0.125f;          // 1/sqrt(64)
    float m = v;
    #pragma unroll
    for (int off = 1; off < 16; off <<= 1) m = fmaxf(m, __shfl_xor(m, off));
    const float e = __expf(v - m);
    float s = e;
    #pragma unroll
    for (int off = 1; off < 16; off <<= 1) s += __shfl_xor(s, off);
    Ps[wid][i * 64 + lane] = e / s;         // == Ps[h*16+g]
  }
  __syncthreads();

  // Stage C: O[h][dd] = sum_g P[h][g] * y[g*64+dd]; lane owns dd = lane.
  float yvr[16];
  #pragma unroll
  for (int g2 = 0; g2 < 16; ++g2) yvr[g2] = ysr[wid][g2 * 64 + lane];

  const size_t rowc = (size_t)b * 4096 + (n >> 4);
  const int    colb = ((n & 15) << 6) + lane;
  #pragma unroll
  for (int hh = 0; hh < 16; ++hh) {
    float o = 0.f;
    #pragma unroll
    for (int g2 = 0; g2 < 16; ++g2) o += Ps[wid][hh * 16 + g2] * yvr[g2];
    A[(rowc + (size_t)hh * 256) * CDIM + colb] = __float2bfloat16(o);
  }
}

// ---------------------------------------------------------------------------
// Kernel 2: W fp32 -> bf16
// ---------------------------------------------------------------------------
__global__ __launch_bounds__(256) void wcvt_kernel(const float* __restrict__ w,
                                                   __hip_bfloat16* __restrict__ wb)
{
  const int i = (blockIdx.x * 256 + threadIdx.x) * 4;
  const float4 v = *(const float4*)(w + i);
  wb[i + 0] = __float2bfloat16(v.x);
  wb[i + 1] = __float2bfloat16(v.y);
  wb[i + 2] = __float2bfloat16(v.z);
  wb[i + 3] = __float2bfloat16(v.w);
}

// ---------------------------------------------------------------------------
// Kernel 3: out[M,N] = A[M,K] * W[N,K]^T + bias, fp32 out.
// m97 structure: 128x128 tile, BK=32, 4 waves (2x2), global_load_lds width 16.
// ---------------------------------------------------------------------------
#define BM 128
#define BN 128
#define BK 32

__global__ __launch_bounds__(256) void gemm_bt_bias(
    const __hip_bfloat16* __restrict__ A,   // [M,K] row-major
    const __hip_bfloat16* __restrict__ Bw,  // [N,K] row-major (= W^T layout)
    const float* __restrict__ bias,         // [N]
    float* __restrict__ C)                  // [M,N]
{
  constexpr int Nn = 1024, K = 1024;
  __shared__ __hip_bfloat16 As[BM * BK];    // 8 KB
  __shared__ __hip_bfloat16 Bs[BN * BK];    // 8 KB

  const int tid  = threadIdx.x;
  const int lane = tid & 63;
  const int wid  = tid >> 6;
  const int wr   = wid >> 1, wc = wid & 1;  // 2x2 wave grid, 64x64 each
  const int mBase = blockIdx.y * BM;
  const int nBase = blockIdx.x * BN;

  // Staging: LDS row-major [128][32] bf16; thread t covers bytes [t*16, t*16+16)
  // => row = t/4 (+64 for second call), elem col = (t%4)*8. Linear in tid, so the
  // per-wave LDS dest is uniform-base + lane*16 as global_load_lds requires.
  const int srow = tid >> 2;
  const int scol = (tid & 3) * 8;
  const __hip_bfloat16* aSrc0 = A  + (size_t)(mBase + srow)      * K + scol;
  const __hip_bfloat16* aSrc1 = A  + (size_t)(mBase + 64 + srow) * K + scol;
  const __hip_bfloat16* bSrc0 = Bw + (size_t)(nBase + srow)      * K + scol;
  const __hip_bfloat16* bSrc1 = Bw + (size_t)(nBase + 64 + srow) * K + scol;
  char* aDst0 = (char*)As + tid * 16;
  char* aDst1 = (char*)As + 4096 + tid * 16;
  char* bDst0 = (char*)Bs + tid * 16;
  char* bDst1 = (char*)Bs + 4096 + tid * 16;

  f32x4 acc[4][4];
  const f32x4 fzero = {0.f, 0.f, 0.f, 0.f};
  #pragma unroll
  for (int m = 0; m < 4; ++m)
    #pragma unroll
    for (int n = 0; n < 4; ++n) acc[m][n] = fzero;

  const int fr = lane & 15;          // fragment row (A) / col (B)
  const int kb = (lane >> 4) * 8;    // k offset within fragment

  for (int k0 = 0; k0 < K; k0 += BK) {
    gload_lds16(aSrc0 + k0, aDst0);
    gload_lds16(aSrc1 + k0, aDst1);
    gload_lds16(bSrc0 + k0, bDst0);
    gload_lds16(bSrc1 + k0, bDst1);
    __syncthreads();                 // compiler drains vmcnt before barrier

    bf16x8 af[4], bfr[4];
    #pragma unroll
    for (int m = 0; m < 4; ++m)
      af[m] = *(const bf16x8*)&As[(wr * 64 + m * 16 + fr) * BK + kb];
    #pragma unroll
    for (int n = 0; n < 4; ++n)
      bfr[n] = *(const bf16x8*)&Bs[(wc * 64 + n * 16 + fr) * BK + kb];

    #pragma unroll
    for (int m = 0; m < 4; ++m)
      #pragma unroll
      for (int n = 0; n < 4; ++n)
        acc[m][n] = __builtin_amdgcn_mfma_f32_16x16x32_bf16(af[m], bfr[n], acc[m][n], 0, 0, 0);
    __syncthreads();                 // all reads done before next stage overwrites
  }

  // Epilogue: C/D layout col=lane&15, row=(lane>>4)*4+reg  [m89-verified]
  const int fq = lane >> 4;
  #pragma unroll
  for (int n = 0; n < 4; ++n) {
    const int col = nBase + wc * 64 + n * 16 + fr;
    const float bv = bias[col];
    #pragma unroll
    for (int m = 0; m < 4; ++m) {
      const int row0 = mBase + wr * 64 + m * 16 + fq * 4;
      #pragma unroll
      for (int r = 0; r < 4; ++r)
        C[(size_t)(row0 + r) * Nn + col] = acc[m][n][r] + bv;
    }
  }
}

extern "C" void kernel_launch(void* const* d_in, const int* in_sizes, int n_in,
                              void* d_out, int out_size, void* d_ws, size_t ws_size,
                              hipStream_t stream) {
  const float* x    = (const float*)d_in[0];
  const float* y    = (const float*)d_in[1];
  const float* W    = (const float*)d_in[2];
  const float* bias = (const float*)d_in[3];
  float* out = (float*)d_out;

  // Workspace: A (16384x1024 bf16 = 32 MB) + Wbf16 (2 MB)
  __hip_bfloat16* Abuf = (__hip_bfloat16*)d_ws;
  __hip_bfloat16* Wbuf = (__hip_bfloat16*)((char*)d_ws + (size_t)16384 * 1024 * 2);

  wcvt_kernel<<<1024, 256, 0, stream>>>(W, Wbuf);
  attn_kernel<<<4096, 256, 0, stream>>>(x, y, Abuf);
  gemm_bt_bias<<<dim3(8, 128), 256, 0, stream>>>(Abuf, Wbuf, bias, out);
}

// Round 2
// 89.403 us; speedup vs baseline: 1.4755x; 1.4755x over previous
//
#include <hip/hip_runtime.h>
#include <hip/hip_bf16.h>
#include <stdint.h>

// Problem constants: B=4, N=4096, C=1024, H=16, d=64
typedef __attribute__((ext_vector_type(8))) short bf16x8;
typedef __attribute__((ext_vector_type(4))) short bf16x4;
typedef __attribute__((ext_vector_type(4))) float f32x4;
typedef __attribute__((ext_vector_type(4))) int   i32x4;

static __device__ __forceinline__ short f2bs(float f) {
  __hip_bfloat16 h = __float2bfloat16(f);
  return __builtin_bit_cast(short, h);
}

__device__ __forceinline__ void gload_lds16(const void* g, void* l) {
  auto* gp = reinterpret_cast<__attribute__((address_space(1))) uint32_t*>((uintptr_t)g);
  auto* lp = reinterpret_cast<__attribute__((address_space(3))) uint32_t*>((uintptr_t)l);
  __builtin_amdgcn_global_load_lds(gp, lp, 16, 0, 0);
}

// ---------------------------------------------------------------------------
// Kernel 1: per-token head-mix attention, fully in registers via MFMA.
// One wave per token. No LDS, no barriers.
//   S^T = mfma(A=Y_heads, B=X_heads): lane holds S[h=lane&15][g=4*(lane>>4)+r]
//   softmax over g: in-reg 4-max + shfl_xor(16), shfl_xor(32)
//   O = P x Y via 16x16x16 MFMA: P registers ARE the A-fragment
// Output bf16 in GEMM layout A[b*4096 + h*256 + n/16][(n%16)*64 + dd].
// ---------------------------------------------------------------------------
__global__ __launch_bounds__(256) void attn_kernel(
    const float* __restrict__ x, const float* __restrict__ y,
    __hip_bfloat16* __restrict__ A)
{
  const int wid  = threadIdx.x >> 6;
  const int lane = threadIdx.x & 63;
  const int tok  = blockIdx.x * 4 + wid;        // 0..16383
  const int b    = tok >> 12;
  const int n    = tok & 4095;

  const float* xr = x + (size_t)tok * 1024;
  const float* yr = y + (size_t)tok * 1024;

  const int c  = lane & 15;                     // fragment row/col index
  const int qq = lane >> 4;                     // k-quad index

  // ---- QK^T fragments straight from global (rows are 4KB, L1-resident) ----
  // A-frag (Y): A[g=c][k=qq*8+j+32kk];  B-frag (X): B[k][h=c] = x[c][k]
  const int fbase = c * 64 + qq * 8;
  bf16x8 yf[2], xf[2];
  #pragma unroll
  for (int kk = 0; kk < 2; ++kk) {
    const float4 a0 = *(const float4*)(yr + fbase + kk * 32);
    const float4 a1 = *(const float4*)(yr + fbase + kk * 32 + 4);
    const float4 b0 = *(const float4*)(xr + fbase + kk * 32);
    const float4 b1 = *(const float4*)(xr + fbase + kk * 32 + 4);
    yf[kk] = bf16x8{f2bs(a0.x), f2bs(a0.y), f2bs(a0.z), f2bs(a0.w),
                    f2bs(a1.x), f2bs(a1.y), f2bs(a1.z), f2bs(a1.w)};
    xf[kk] = bf16x8{f2bs(b0.x), f2bs(b0.y), f2bs(b0.z), f2bs(b0.w),
                    f2bs(b1.x), f2bs(b1.y), f2bs(b1.z), f2bs(b1.w)};
  }

  f32x4 acc = {0.f, 0.f, 0.f, 0.f};
  acc = __builtin_amdgcn_mfma_f32_16x16x32_bf16(yf[0], xf[0], acc, 0, 0, 0);
  acc = __builtin_amdgcn_mfma_f32_16x16x32_bf16(yf[1], xf[1], acc, 0, 0, 0);
  // lane now holds S[h=c][g=4*qq+r] (r = reg index)

  // ---- softmax over g (rows of S live across lanes l, l^16, l^32, l^48) ----
  float sc[4];
  #pragma unroll
  for (int r = 0; r < 4; ++r) sc[r] = acc[r] * 0.125f;   // 1/sqrt(64)
  float mx = fmaxf(fmaxf(sc[0], sc[1]), fmaxf(sc[2], sc[3]));
  mx = fmaxf(mx, __shfl_xor(mx, 16));
  mx = fmaxf(mx, __shfl_xor(mx, 32));
  float e[4];
  #pragma unroll
  for (int r = 0; r < 4; ++r) e[r] = __expf(sc[r] - mx);
  float sm = (e[0] + e[1]) + (e[2] + e[3]);
  sm += __shfl_xor(sm, 16);
  sm += __shfl_xor(sm, 32);
  const float inv = 1.0f / sm;
  float p[4];
  #pragma unroll
  for (int r = 0; r < 4; ++r) p[r] = e[r] * inv;
  // lane holds P[h=c][g=4*qq+r]

  // ---- PV: O[h][dd] = sum_g P[h][g] * y[g][dd] ----
  f32x4 o[4];
  #pragma unroll
  for (int q = 0; q < 4; ++q) o[q] = f32x4{0.f, 0.f, 0.f, 0.f};

#if __has_builtin(__builtin_amdgcn_mfma_f32_16x16x16bf16_1k)
  // P registers are exactly the 16x16x16 A-fragment: A[m=c][k=4*qq+j].
  const bf16x4 pa = {f2bs(p[0]), f2bs(p[1]), f2bs(p[2]), f2bs(p[3])};
  #pragma unroll
  for (int q = 0; q < 4; ++q) {
    bf16x4 bq;
    #pragma unroll
    for (int j = 0; j < 4; ++j)
      bq[j] = f2bs(yr[(qq * 4 + j) * 64 + q * 16 + c]);  // B[k=g][n=c]
    o[q] = __builtin_amdgcn_mfma_f32_16x16x16bf16_1k(pa, bq, o[q], 0, 0, 0);
  }
#else
  // Fallback: zero-padded K=32. A-frag needs A[m=c][k=8qq+j]: gather the two
  // g-quads from lanes c+32*qq and c+32*qq+16 (qq<2), zeros for qq>=2.
  const int u0 = ((int)(unsigned short)f2bs(p[1]) << 16) | (unsigned short)f2bs(p[0]);
  const int u1 = ((int)(unsigned short)f2bs(p[3]) << 16) | (unsigned short)f2bs(p[2]);
  const int s0 = c + 32 * qq;
  int a0 = __shfl(u0, s0), a1 = __shfl(u1, s0);
  int a2 = __shfl(u0, s0 + 16), a3 = __shfl(u1, s0 + 16);
  const bool valid = (qq < 2);
  if (!valid) { a0 = 0; a1 = 0; a2 = 0; a3 = 0; }
  const bf16x8 a8 = __builtin_bit_cast(bf16x8, i32x4{a0, a1, a2, a3});
  #pragma unroll
  for (int q = 0; q < 4; ++q) {
    bf16x8 b8;
    #pragma unroll
    for (int j = 0; j < 8; ++j) {
      const int g = (qq * 8 + j) & 15;
      const float v = yr[g * 64 + q * 16 + c];
      b8[j] = valid ? f2bs(v) : (short)0;
    }
    o[q] = __builtin_amdgcn_mfma_f32_16x16x32_bf16(a8, b8, o[q], 0, 0, 0);
  }
#endif
  // lane holds O[h=4*qq+r][dd=q*16+c]

  // ---- store bf16 in the scrambled GEMM layout ----
  const size_t base = ((size_t)b * 4096 + (n >> 4)) * 1024 + ((n & 15) << 6) + c;
  #pragma unroll
  for (int q = 0; q < 4; ++q)
    #pragma unroll
    for (int r = 0; r < 4; ++r) {
      const int h = qq * 4 + r;
      A[base + (size_t)h * 262144 + q * 16] = __float2bfloat16(o[q][r]);
    }
}

// ---------------------------------------------------------------------------
// Kernel 2: W fp32 -> bf16
// ---------------------------------------------------------------------------
__global__ __launch_bounds__(256) void wcvt_kernel(const float* __restrict__ w,
                                                   __hip_bfloat16* __restrict__ wb)
{
  const int i = (blockIdx.x * 256 + threadIdx.x) * 4;
  const float4 v = *(const float4*)(w + i);
  wb[i + 0] = __float2bfloat16(v.x);
  wb[i + 1] = __float2bfloat16(v.y);
  wb[i + 2] = __float2bfloat16(v.z);
  wb[i + 3] = __float2bfloat16(v.w);
}

// ---------------------------------------------------------------------------
// Kernel 3: out[M,N] = A[M,K] * W[N,K]^T + bias, fp32 out.
// m97 structure: 128x128 tile, BK=32, 4 waves (2x2), global_load_lds width 16.
// + bijective XCD-chunked block swizzle (grid = 8 x 128 = 1024, 1024%8==0).
// ---------------------------------------------------------------------------
#define BM 128
#define BN 128
#define BK 32

__global__ __launch_bounds__(256) void gemm_bt_bias(
    const __hip_bfloat16* __restrict__ A,   // [M,K] row-major
    const __hip_bfloat16* __restrict__ Bw,  // [N,K] row-major (= W^T layout)
    const float* __restrict__ bias,         // [N]
    float* __restrict__ C)                  // [M,N]
{
  constexpr int Nn = 1024, K = 1024;
  __shared__ __hip_bfloat16 As[BM * BK];    // 8 KB
  __shared__ __hip_bfloat16 Bs[BN * BK];    // 8 KB

  const int tid  = threadIdx.x;
  const int lane = tid & 63;
  const int wid  = tid >> 6;
  const int wr   = wid >> 1, wc = wid & 1;  // 2x2 wave grid, 64x64 each

  // XCD-chunked swizzle: each XCD gets 16 contiguous M-tiles (A-panel + W reuse in L2)
  const int bid = blockIdx.y * 8 + blockIdx.x;     // grid is dim3(8,128)
  const int nb  = (bid & 7) * 128 + (bid >> 3);
  const int mBase = (nb >> 3) * BM;
  const int nBase = (nb & 7) * BN;

  // Staging: LDS row-major [128][32] bf16; thread t covers bytes [t*16, t*16+16)
  const int srow = tid >> 2;
  const int scol = (tid & 3) * 8;
  const __hip_bfloat16* aSrc0 = A  + (size_t)(mBase + srow)      * K + scol;
  const __hip_bfloat16* aSrc1 = A  + (size_t)(mBase + 64 + srow) * K + scol;
  const __hip_bfloat16* bSrc0 = Bw + (size_t)(nBase + srow)      * K + scol;
  const __hip_bfloat16* bSrc1 = Bw + (size_t)(nBase + 64 + srow) * K + scol;
  char* aDst0 = (char*)As + tid * 16;
  char* aDst1 = (char*)As + 4096 + tid * 16;
  char* bDst0 = (char*)Bs + tid * 16;
  char* bDst1 = (char*)Bs + 4096 + tid * 16;

  f32x4 acc[4][4];
  const f32x4 fzero = {0.f, 0.f, 0.f, 0.f};
  #pragma unroll
  for (int m = 0; m < 4; ++m)
    #pragma unroll
    for (int n = 0; n < 4; ++n) acc[m][n] = fzero;

  const int fr = lane & 15;          // fragment row (A) / col (B)
  const int kb = (lane >> 4) * 8;    // k offset within fragment

  for (int k0 = 0; k0 < K; k0 += BK) {
    gload_lds16(aSrc0 + k0, aDst0);
    gload_lds16(aSrc1 + k0, aDst1);
    gload_lds16(bSrc0 + k0, bDst0);
    gload_lds16(bSrc1 + k0, bDst1);
    __syncthreads();

    bf16x8 af[4], bfr[4];
    #pragma unroll
    for (int m = 0; m < 4; ++m)
      af[m] = *(const bf16x8*)&As[(wr * 64 + m * 16 + fr) * BK + kb];
    #pragma unroll
    for (int n = 0; n < 4; ++n)
      bfr[n] = *(const bf16x8*)&Bs[(wc * 64 + n * 16 + fr) * BK + kb];

    #pragma unroll
    for (int m = 0; m < 4; ++m)
      #pragma unroll
      for (int n = 0; n < 4; ++n)
        acc[m][n] = __builtin_amdgcn_mfma_f32_16x16x32_bf16(af[m], bfr[n], acc[m][n], 0, 0, 0);
    __syncthreads();
  }

  // Epilogue: C/D layout col=lane&15, row=(lane>>4)*4+reg  [m89-verified]
  const int fq = lane >> 4;
  #pragma unroll
  for (int n = 0; n < 4; ++n) {
    const int col = nBase + wc * 64 + n * 16 + fr;
    const float bv = bias[col];
    #pragma unroll
    for (int m = 0; m < 4; ++m) {
      const int row0 = mBase + wr * 64 + m * 16 + fq * 4;
      #pragma unroll
      for (int r = 0; r < 4; ++r)
        C[(size_t)(row0 + r) * Nn + col] = acc[m][n][r] + bv;
    }
  }
}

extern "C" void kernel_launch(void* const* d_in, const int* in_sizes, int n_in,
                              void* d_out, int out_size, void* d_ws, size_t ws_size,
                              hipStream_t stream) {
  const float* x    = (const float*)d_in[0];
  const float* y    = (const float*)d_in[1];
  const float* W    = (const float*)d_in[2];
  const float* bias = (const float*)d_in[3];
  float* out = (float*)d_out;

  // Workspace: A (16384x1024 bf16 = 32 MB) + Wbf16 (2 MB)
  __hip_bfloat16* Abuf = (__hip_bfloat16*)d_ws;
  __hip_bfloat16* Wbuf = (__hip_bfloat16*)((char*)d_ws + (size_t)16384 * 1024 * 2);

  wcvt_kernel<<<1024, 256, 0, stream>>>(W, Wbuf);
  attn_kernel<<<4096, 256, 0, stream>>>(x, y, Abuf);
  gemm_bt_bias<<<dim3(8, 128), 256, 0, stream>>>(Abuf, Wbuf, bias, out);
}

// Round 3
// 76.385 us; speedup vs baseline: 1.7270x; 1.1704x over previous
//
#include <hip/hip_runtime.h>
#include <hip/hip_bf16.h>
#include <stdint.h>

// Problem constants: B=4, N=4096, C=1024, H=16, d=64
typedef __attribute__((ext_vector_type(8))) short bf16x8;
typedef __attribute__((ext_vector_type(4))) short bf16x4;
typedef __attribute__((ext_vector_type(4))) float f32x4;
typedef __attribute__((ext_vector_type(4))) int   i32x4;

static __device__ __forceinline__ short f2bs(float f) {
  __hip_bfloat16 h = __float2bfloat16(f);
  return __builtin_bit_cast(short, h);
}

__device__ __forceinline__ void gload_lds16(const void* g, void* l) {
  auto* gp = reinterpret_cast<__attribute__((address_space(1))) uint32_t*>((uintptr_t)g);
  auto* lp = reinterpret_cast<__attribute__((address_space(3))) uint32_t*>((uintptr_t)l);
  __builtin_amdgcn_global_load_lds(gp, lp, 16, 0, 0);
}

// ---------------------------------------------------------------------------
// Kernel 1: per-token head-mix attention, fully in registers via MFMA.
// (unchanged from R1 — runs at its memory floor)
// ---------------------------------------------------------------------------
__global__ __launch_bounds__(256) void attn_kernel(
    const float* __restrict__ x, const float* __restrict__ y,
    __hip_bfloat16* __restrict__ A)
{
  const int wid  = threadIdx.x >> 6;
  const int lane = threadIdx.x & 63;
  const int tok  = blockIdx.x * 4 + wid;        // 0..16383
  const int b    = tok >> 12;
  const int n    = tok & 4095;

  const float* xr = x + (size_t)tok * 1024;
  const float* yr = y + (size_t)tok * 1024;

  const int c  = lane & 15;
  const int qq = lane >> 4;

  const int fbase = c * 64 + qq * 8;
  bf16x8 yf[2], xf[2];
  #pragma unroll
  for (int kk = 0; kk < 2; ++kk) {
    const float4 a0 = *(const float4*)(yr + fbase + kk * 32);
    const float4 a1 = *(const float4*)(yr + fbase + kk * 32 + 4);
    const float4 b0 = *(const float4*)(xr + fbase + kk * 32);
    const float4 b1 = *(const float4*)(xr + fbase + kk * 32 + 4);
    yf[kk] = bf16x8{f2bs(a0.x), f2bs(a0.y), f2bs(a0.z), f2bs(a0.w),
                    f2bs(a1.x), f2bs(a1.y), f2bs(a1.z), f2bs(a1.w)};
    xf[kk] = bf16x8{f2bs(b0.x), f2bs(b0.y), f2bs(b0.z), f2bs(b0.w),
                    f2bs(b1.x), f2bs(b1.y), f2bs(b1.z), f2bs(b1.w)};
  }

  f32x4 acc = {0.f, 0.f, 0.f, 0.f};
  acc = __builtin_amdgcn_mfma_f32_16x16x32_bf16(yf[0], xf[0], acc, 0, 0, 0);
  acc = __builtin_amdgcn_mfma_f32_16x16x32_bf16(yf[1], xf[1], acc, 0, 0, 0);

  float sc[4];
  #pragma unroll
  for (int r = 0; r < 4; ++r) sc[r] = acc[r] * 0.125f;
  float mx = fmaxf(fmaxf(sc[0], sc[1]), fmaxf(sc[2], sc[3]));
  mx = fmaxf(mx, __shfl_xor(mx, 16));
  mx = fmaxf(mx, __shfl_xor(mx, 32));
  float e[4];
  #pragma unroll
  for (int r = 0; r < 4; ++r) e[r] = __expf(sc[r] - mx);
  float sm = (e[0] + e[1]) + (e[2] + e[3]);
  sm += __shfl_xor(sm, 16);
  sm += __shfl_xor(sm, 32);
  const float inv = 1.0f / sm;
  float p[4];
  #pragma unroll
  for (int r = 0; r < 4; ++r) p[r] = e[r] * inv;

  f32x4 o[4];
  #pragma unroll
  for (int q = 0; q < 4; ++q) o[q] = f32x4{0.f, 0.f, 0.f, 0.f};

#if __has_builtin(__builtin_amdgcn_mfma_f32_16x16x16bf16_1k)
  const bf16x4 pa = {f2bs(p[0]), f2bs(p[1]), f2bs(p[2]), f2bs(p[3])};
  #pragma unroll
  for (int q = 0; q < 4; ++q) {
    bf16x4 bq;
    #pragma unroll
    for (int j = 0; j < 4; ++j)
      bq[j] = f2bs(yr[(qq * 4 + j) * 64 + q * 16 + c]);
    o[q] = __builtin_amdgcn_mfma_f32_16x16x16bf16_1k(pa, bq, o[q], 0, 0, 0);
  }
#else
  const int u0 = ((int)(unsigned short)f2bs(p[1]) << 16) | (unsigned short)f2bs(p[0]);
  const int u1 = ((int)(unsigned short)f2bs(p[3]) << 16) | (unsigned short)f2bs(p[2]);
  const int s0 = c + 32 * qq;
  int a0 = __shfl(u0, s0), a1 = __shfl(u1, s0);
  int a2 = __shfl(u0, s0 + 16), a3 = __shfl(u1, s0 + 16);
  const bool valid = (qq < 2);
  if (!valid) { a0 = 0; a1 = 0; a2 = 0; a3 = 0; }
  const bf16x8 a8 = __builtin_bit_cast(bf16x8, i32x4{a0, a1, a2, a3});
  #pragma unroll
  for (int q = 0; q < 4; ++q) {
    bf16x8 b8;
    #pragma unroll
    for (int j = 0; j < 8; ++j) {
      const int g = (qq * 8 + j) & 15;
      const float v = yr[g * 64 + q * 16 + c];
      b8[j] = valid ? f2bs(v) : (short)0;
    }
    o[q] = __builtin_amdgcn_mfma_f32_16x16x32_bf16(a8, b8, o[q], 0, 0, 0);
  }
#endif

  const size_t base = ((size_t)b * 4096 + (n >> 4)) * 1024 + ((n & 15) << 6) + c;
  #pragma unroll
  for (int q = 0; q < 4; ++q)
    #pragma unroll
    for (int r = 0; r < 4; ++r) {
      const int h = qq * 4 + r;
      A[base + (size_t)h * 262144 + q * 16] = __float2bfloat16(o[q][r]);
    }
}

// ---------------------------------------------------------------------------
// Kernel 2: W fp32 -> bf16
// ---------------------------------------------------------------------------
__global__ __launch_bounds__(256) void wcvt_kernel(const float* __restrict__ w,
                                                   __hip_bfloat16* __restrict__ wb)
{
  const int i = (blockIdx.x * 256 + threadIdx.x) * 4;
  const float4 v = *(const float4*)(w + i);
  wb[i + 0] = __float2bfloat16(v.x);
  wb[i + 1] = __float2bfloat16(v.y);
  wb[i + 2] = __float2bfloat16(v.z);
  wb[i + 3] = __float2bfloat16(v.w);
}

// ---------------------------------------------------------------------------
// Kernel 3: out[M,Nn] = A[M,K] * Bw[Nn,K]^T + bias, fp32 out.
// 256x256 tile, BK=64, 8 waves (2Mx4N), 128 KiB double-buffered LDS,
// 4-phase/K-tile schedule (T3+T4), XOR LDS swizzle (T2, both-sides),
// setprio around MFMA clusters (T5), counted vmcnt (one drain per K-tile),
// bijective XCD-chunked block swizzle (T1). Raw s_barrier (no syncthreads).
// ---------------------------------------------------------------------------
#define NT 16   // K / 64

#define FENCE asm volatile("" ::: "memory")
#define BAR   __builtin_amdgcn_s_barrier()

#define STAGE_A(toff, b) do {                                           \
    gload_lds16(aSrc + (toff),          aDst + (b) * 32768);            \
    gload_lds16(aSrc + (toff) + 131072, aDst + (b) * 32768 + 8192);     \
    gload_lds16(aSrc + (toff) + 262144, aDst + (b) * 32768 + 16384);    \
    gload_lds16(aSrc + (toff) + 393216, aDst + (b) * 32768 + 24576);    \
  } while (0)

#define STAGE_B(toff, b) do {                                           \
    gload_lds16(bSrc + (toff),          bDst + (b) * 32768);            \
    gload_lds16(bSrc + (toff) + 131072, bDst + (b) * 32768 + 8192);     \
    gload_lds16(bSrc + (toff) + 262144, bDst + (b) * 32768 + 16384);    \
    gload_lds16(bSrc + (toff) + 393216, bDst + (b) * 32768 + 24576);    \
  } while (0)

__global__ __launch_bounds__(512, 2) void gemm256(
    const __hip_bfloat16* __restrict__ A,   // [M,K] row-major bf16
    const __hip_bfloat16* __restrict__ Bw,  // [Nn,K] row-major bf16 (= W^T layout)
    const float* __restrict__ bias,         // [Nn]
    float* __restrict__ C)                  // [M,Nn] fp32
{
  constexpr int K = 1024, Nn = 1024;
  __shared__ char ldsA[2 * 32768];          // [buf][256 rows][128B], swizzled
  __shared__ char ldsB[2 * 32768];

  const int tid  = threadIdx.x;             // 0..511
  const int lane = tid & 63;
  const int wid  = tid >> 6;                // 8 waves
  const int wr   = wid >> 2;                // 0..1  (M half: 128 rows)
  const int wc   = wid & 3;                 // 0..3  (N quarter: 64 cols)

  // XCD-chunked bijective swizzle: 256 blocks, 8 XCDs x 32 contiguous tiles.
  const int bid = blockIdx.x;
  const int nb  = (bid & 7) * 32 + (bid >> 3);
  const int mBase = (nb >> 2) * 256;        // 64 M-tiles
  const int nBase = (nb & 3) * 256;         // 4 N-tiles

  // ---- staging geometry: linear LDS dest, pre-swizzled global source ----
  // physical tile byte p = issue*8192 + tid*16; row = p>>7; physColByte = p&127
  // logical colbyte = physColByte ^ ((row&7)<<4)   [involution, 16B-chunk safe]
  const int srow = tid >> 3;                // row within 64-row issue chunk
  const int pcb  = (tid & 7) << 4;
  const int lcb  = pcb ^ ((srow & 7) << 4);
  const char* aSrc = (const char*)A  + ((size_t)(mBase + srow) * K) * 2 + lcb;
  const char* bSrc = (const char*)Bw + ((size_t)(nBase + srow) * K) * 2 + lcb;
  char* aDst = ldsA + tid * 16;
  char* bDst = ldsB + tid * 16;

  // ---- ds_read geometry (swizzled) ----
  const int fr = lane & 15;                 // fragment row
  const int kq = lane >> 4;                 // k-quad
  const int xr = (fr & 7) << 4;
  const int ofk0 = ((kq << 4))      ^ xr;   // k-half 0 colbyte
  const int ofk1 = (64 + (kq << 4)) ^ xr;   // k-half 1 colbyte
  const char* aRow = ldsA + (wr * 128 + fr) * 128;
  const char* bRow = ldsB + (wc * 64  + fr) * 128;

  f32x4 acc[8][4];
  #pragma unroll
  for (int m = 0; m < 8; ++m)
    #pragma unroll
    for (int n = 0; n < 4; ++n) acc[m][n] = f32x4{0.f, 0.f, 0.f, 0.f};

  // ---- prologue: stage tile 0, drain, barrier ----
  STAGE_A(0, 0);
  STAGE_B(0, 0);
  asm volatile("s_waitcnt vmcnt(0)" ::: "memory");
  BAR;

  for (int t = 0; t < NT; ++t) {
    const int cur  = t & 1;
    const int nxt  = cur ^ 1;
    const int toff = (t + 1) * 128;
    const char* aR = aRow + cur * 32768;
    const char* bR = bRow + cur * 32768;
    bf16x8 Af[4], Bf[4];

    // ===== phase 1: k-half 0, m0-3 x n0-3; issue A-stage for t+1 =====
    if (t + 1 < NT) STAGE_A(toff, nxt);
    #pragma unroll
    for (int n = 0; n < 4; ++n) Bf[n] = *(const bf16x8*)(bR + n * 2048 + ofk0);
    #pragma unroll
    for (int m = 0; m < 4; ++m) Af[m] = *(const bf16x8*)(aR + m * 2048 + ofk0);
    FENCE; BAR;
    asm volatile("s_waitcnt lgkmcnt(0)" ::: "memory");
    __builtin_amdgcn_sched_barrier(0);
    __builtin_amdgcn_s_setprio(1);
    #pragma unroll
    for (int m = 0; m < 4; ++m)
      #pragma unroll
      for (int n = 0; n < 4; ++n)
        acc[m][n] = __builtin_amdgcn_mfma_f32_16x16x32_bf16(Af[m], Bf[n], acc[m][n], 0, 0, 0);
    __builtin_amdgcn_s_setprio(0);
    FENCE; BAR;

    // ===== phase 2: k-half 0, m4-7 x n0-3 (reuse Bf); issue B-stage =====
    if (t + 1 < NT) STAGE_B(toff, nxt);
    #pragma unroll
    for (int m = 0; m < 4; ++m) Af[m] = *(const bf16x8*)(aR + (4 + m) * 2048 + ofk0);
    FENCE; BAR;
    asm volatile("s_waitcnt lgkmcnt(0)" ::: "memory");
    __builtin_amdgcn_sched_barrier(0);
    __builtin_amdgcn_s_setprio(1);
    #pragma unroll
    for (int m = 0; m < 4; ++m)
      #pragma unroll
      for (int n = 0; n < 4; ++n)
        acc[4 + m][n] = __builtin_amdgcn_mfma_f32_16x16x32_bf16(Af[m], Bf[n], acc[4 + m][n], 0, 0, 0);
    __builtin_amdgcn_s_setprio(0);
    FENCE; BAR;

    // ===== phase 3: k-half 1, m0-3 x n0-3 =====
    #pragma unroll
    for (int n = 0; n < 4; ++n) Bf[n] = *(const bf16x8*)(bR + n * 2048 + ofk1);
    #pragma unroll
    for (int m = 0; m < 4; ++m) Af[m] = *(const bf16x8*)(aR + m * 2048 + ofk1);
    FENCE; BAR;
    asm volatile("s_waitcnt lgkmcnt(0)" ::: "memory");
    __builtin_amdgcn_sched_barrier(0);
    __builtin_amdgcn_s_setprio(1);
    #pragma unroll
    for (int m = 0; m < 4; ++m)
      #pragma unroll
      for (int n = 0; n < 4; ++n)
        acc[m][n] = __builtin_amdgcn_mfma_f32_16x16x32_bf16(Af[m], Bf[n], acc[m][n], 0, 0, 0);
    __builtin_amdgcn_s_setprio(0);
    FENCE; BAR;

    // ===== phase 4: k-half 1, m4-7 x n0-3; drain stage loads, flip =====
    #pragma unroll
    for (int m = 0; m < 4; ++m) Af[m] = *(const bf16x8*)(aR + (4 + m) * 2048 + ofk1);
    FENCE; BAR;
    asm volatile("s_waitcnt lgkmcnt(0)" ::: "memory");
    __builtin_amdgcn_sched_barrier(0);
    __builtin_amdgcn_s_setprio(1);
    #pragma unroll
    for (int m = 0; m < 4; ++m)
      #pragma unroll
      for (int n = 0; n < 4; ++n)
        acc[4 + m][n] = __builtin_amdgcn_mfma_f32_16x16x32_bf16(Af[m], Bf[n], acc[4 + m][n], 0, 0, 0);
    __builtin_amdgcn_s_setprio(0);
    if (t + 1 < NT) asm volatile("s_waitcnt vmcnt(0)" ::: "memory");
    FENCE; BAR;
  }

  // ---- epilogue: C/D layout col=lane&15, row=(lane>>4)*4+reg ----
  const int fq = lane >> 4;
  #pragma unroll
  for (int n = 0; n < 4; ++n) {
    const int col = nBase + wc * 64 + n * 16 + fr;
    const float bv = bias[col];
    #pragma unroll
    for (int m = 0; m < 8; ++m) {
      const int row0 = mBase + wr * 128 + m * 16 + fq * 4;
      #pragma unroll
      for (int r = 0; r < 4; ++r)
        C[(size_t)(row0 + r) * Nn + col] = acc[m][n][r] + bv;
    }
  }
}

extern "C" void kernel_launch(void* const* d_in, const int* in_sizes, int n_in,
                              void* d_out, int out_size, void* d_ws, size_t ws_size,
                              hipStream_t stream) {
  const float* x    = (const float*)d_in[0];
  const float* y    = (const float*)d_in[1];
  const float* W    = (const float*)d_in[2];
  const float* bias = (const float*)d_in[3];
  float* out = (float*)d_out;

  // Workspace: A (16384x1024 bf16 = 32 MB) + Wbf16 (2 MB)
  __hip_bfloat16* Abuf = (__hip_bfloat16*)d_ws;
  __hip_bfloat16* Wbuf = (__hip_bfloat16*)((char*)d_ws + (size_t)16384 * 1024 * 2);

  wcvt_kernel<<<1024, 256, 0, stream>>>(W, Wbuf);
  attn_kernel<<<4096, 256, 0, stream>>>(x, y, Abuf);
  gemm256<<<256, 512, 0, stream>>>(Abuf, Wbuf, bias, out);
}

// Round 4
// 74.539 us; speedup vs baseline: 1.7698x; 1.0248x over previous
//
#include <hip/hip_runtime.h>
#include <hip/hip_bf16.h>
#include <stdint.h>

// Problem constants: B=4, N=4096, C=1024, H=16, d=64
typedef __attribute__((ext_vector_type(8))) short bf16x8;
typedef __attribute__((ext_vector_type(4))) short bf16x4;
typedef __attribute__((ext_vector_type(4))) float f32x4;
typedef __attribute__((ext_vector_type(4))) int   i32x4;

static __device__ __forceinline__ short f2bs(float f) {
  __hip_bfloat16 h = __float2bfloat16(f);
  return __builtin_bit_cast(short, h);
}

__device__ __forceinline__ void gload_lds16(const void* g, void* l) {
  auto* gp = reinterpret_cast<__attribute__((address_space(1))) uint32_t*>((uintptr_t)g);
  auto* lp = reinterpret_cast<__attribute__((address_space(3))) uint32_t*>((uintptr_t)l);
  __builtin_amdgcn_global_load_lds(gp, lp, 16, 0, 0);
}

// ---------------------------------------------------------------------------
// Kernel 1: per-token head-mix attention, fully in registers via MFMA.
// (unchanged — near its L3-warm memory floor in the timed run)
// ---------------------------------------------------------------------------
__global__ __launch_bounds__(256) void attn_kernel(
    const float* __restrict__ x, const float* __restrict__ y,
    __hip_bfloat16* __restrict__ A)
{
  const int wid  = threadIdx.x >> 6;
  const int lane = threadIdx.x & 63;
  const int tok  = blockIdx.x * 4 + wid;        // 0..16383
  const int b    = tok >> 12;
  const int n    = tok & 4095;

  const float* xr = x + (size_t)tok * 1024;
  const float* yr = y + (size_t)tok * 1024;

  const int c  = lane & 15;
  const int qq = lane >> 4;

  const int fbase = c * 64 + qq * 8;
  bf16x8 yf[2], xf[2];
  #pragma unroll
  for (int kk = 0; kk < 2; ++kk) {
    const float4 a0 = *(const float4*)(yr + fbase + kk * 32);
    const float4 a1 = *(const float4*)(yr + fbase + kk * 32 + 4);
    const float4 b0 = *(const float4*)(xr + fbase + kk * 32);
    const float4 b1 = *(const float4*)(xr + fbase + kk * 32 + 4);
    yf[kk] = bf16x8{f2bs(a0.x), f2bs(a0.y), f2bs(a0.z), f2bs(a0.w),
                    f2bs(a1.x), f2bs(a1.y), f2bs(a1.z), f2bs(a1.w)};
    xf[kk] = bf16x8{f2bs(b0.x), f2bs(b0.y), f2bs(b0.z), f2bs(b0.w),
                    f2bs(b1.x), f2bs(b1.y), f2bs(b1.z), f2bs(b1.w)};
  }

  f32x4 acc = {0.f, 0.f, 0.f, 0.f};
  acc = __builtin_amdgcn_mfma_f32_16x16x32_bf16(yf[0], xf[0], acc, 0, 0, 0);
  acc = __builtin_amdgcn_mfma_f32_16x16x32_bf16(yf[1], xf[1], acc, 0, 0, 0);

  float sc[4];
  #pragma unroll
  for (int r = 0; r < 4; ++r) sc[r] = acc[r] * 0.125f;
  float mx = fmaxf(fmaxf(sc[0], sc[1]), fmaxf(sc[2], sc[3]));
  mx = fmaxf(mx, __shfl_xor(mx, 16));
  mx = fmaxf(mx, __shfl_xor(mx, 32));
  float e[4];
  #pragma unroll
  for (int r = 0; r < 4; ++r) e[r] = __expf(sc[r] - mx);
  float sm = (e[0] + e[1]) + (e[2] + e[3]);
  sm += __shfl_xor(sm, 16);
  sm += __shfl_xor(sm, 32);
  const float inv = 1.0f / sm;
  float p[4];
  #pragma unroll
  for (int r = 0; r < 4; ++r) p[r] = e[r] * inv;

  f32x4 o[4];
  #pragma unroll
  for (int q = 0; q < 4; ++q) o[q] = f32x4{0.f, 0.f, 0.f, 0.f};

#if __has_builtin(__builtin_amdgcn_mfma_f32_16x16x16bf16_1k)
  const bf16x4 pa = {f2bs(p[0]), f2bs(p[1]), f2bs(p[2]), f2bs(p[3])};
  #pragma unroll
  for (int q = 0; q < 4; ++q) {
    bf16x4 bq;
    #pragma unroll
    for (int j = 0; j < 4; ++j)
      bq[j] = f2bs(yr[(qq * 4 + j) * 64 + q * 16 + c]);
    o[q] = __builtin_amdgcn_mfma_f32_16x16x16bf16_1k(pa, bq, o[q], 0, 0, 0);
  }
#else
  const int u0 = ((int)(unsigned short)f2bs(p[1]) << 16) | (unsigned short)f2bs(p[0]);
  const int u1 = ((int)(unsigned short)f2bs(p[3]) << 16) | (unsigned short)f2bs(p[2]);
  const int s0 = c + 32 * qq;
  int a0 = __shfl(u0, s0), a1 = __shfl(u1, s0);
  int a2 = __shfl(u0, s0 + 16), a3 = __shfl(u1, s0 + 16);
  const bool valid = (qq < 2);
  if (!valid) { a0 = 0; a1 = 0; a2 = 0; a3 = 0; }
  const bf16x8 a8 = __builtin_bit_cast(bf16x8, i32x4{a0, a1, a2, a3});
  #pragma unroll
  for (int q = 0; q < 4; ++q) {
    bf16x8 b8;
    #pragma unroll
    for (int j = 0; j < 8; ++j) {
      const int g = (qq * 8 + j) & 15;
      const float v = yr[g * 64 + q * 16 + c];
      b8[j] = valid ? f2bs(v) : (short)0;
    }
    o[q] = __builtin_amdgcn_mfma_f32_16x16x32_bf16(a8, b8, o[q], 0, 0, 0);
  }
#endif

  const size_t base = ((size_t)b * 4096 + (n >> 4)) * 1024 + ((n & 15) << 6) + c;
  #pragma unroll
  for (int q = 0; q < 4; ++q)
    #pragma unroll
    for (int r = 0; r < 4; ++r) {
      const int h = qq * 4 + r;
      A[base + (size_t)h * 262144 + q * 16] = __float2bfloat16(o[q][r]);
    }
}

// ---------------------------------------------------------------------------
// Kernel 2: W fp32 -> bf16
// ---------------------------------------------------------------------------
__global__ __launch_bounds__(256) void wcvt_kernel(const float* __restrict__ w,
                                                   __hip_bfloat16* __restrict__ wb)
{
  const int i = (blockIdx.x * 256 + threadIdx.x) * 4;
  const float4 v = *(const float4*)(w + i);
  wb[i + 0] = __float2bfloat16(v.x);
  wb[i + 1] = __float2bfloat16(v.y);
  wb[i + 2] = __float2bfloat16(v.z);
  wb[i + 3] = __float2bfloat16(v.w);
}

// ---------------------------------------------------------------------------
// Kernel 3: out[M,Nn] = A[M,K] * Bw[Nn,K]^T + bias, fp32 out.
// 128x128 tile, BK=64, 8 waves (2M x 4N, wave tile 64x32), 64 KiB dbuf LDS
// -> 2 blocks/CU (cross-block overlap of epilogue/prologue/drains).
// 2 phases per K-tile, T2 both-sides XOR swizzle, T5 setprio, one
// vmcnt(0)+barrier per tile, bijective XCD chunking. 1024 blocks.
// ---------------------------------------------------------------------------
#define NT 16   // K / 64

#define FENCE asm volatile("" ::: "memory")
#define BAR   __builtin_amdgcn_s_barrier()

#define STAGE_A(toff, b) do {                                           \
    gload_lds16(aSrc + (toff),          aDst + (b) * 16384);            \
    gload_lds16(aSrc + (toff) + 131072, aDst + (b) * 16384 + 8192);     \
  } while (0)

#define STAGE_B(toff, b) do {                                           \
    gload_lds16(bSrc + (toff),          bDst + (b) * 16384);            \
    gload_lds16(bSrc + (toff) + 131072, bDst + (b) * 16384 + 8192);     \
  } while (0)

__global__ __launch_bounds__(512, 4) void gemm128(
    const __hip_bfloat16* __restrict__ A,   // [M,K] row-major bf16
    const __hip_bfloat16* __restrict__ Bw,  // [Nn,K] row-major bf16 (= W^T layout)
    const float* __restrict__ bias,         // [Nn]
    float* __restrict__ C)                  // [M,Nn] fp32
{
  constexpr int K = 1024, Nn = 1024;
  __shared__ char ldsA[2 * 16384];          // [buf][128 rows][128B], swizzled
  __shared__ char ldsB[2 * 16384];

  const int tid  = threadIdx.x;             // 0..511
  const int lane = tid & 63;
  const int wid  = tid >> 6;                // 8 waves
  const int wr   = wid >> 2;                // 0..1  (M half: 64 rows)
  const int wc   = wid & 3;                 // 0..3  (N quarter: 32 cols)

  // XCD-chunked bijective swizzle: 1024 blocks, 8 XCDs x 128 contiguous tiles.
  const int bid = blockIdx.x;
  const int nb  = (bid & 7) * 128 + (bid >> 3);
  const int mBase = (nb >> 3) * 128;        // 128 M-tiles
  const int nBase = (nb & 7) * 128;         // 8 N-tiles

  // ---- staging geometry: linear LDS dest, pre-swizzled global source ----
  // tile byte p = issue*8192 + tid*16; row = p>>7; physColByte = p&127
  // logical colbyte = physColByte ^ ((row&7)<<4)   [involution]
  const int srow = tid >> 3;                // row within 64-row issue chunk
  const int pcb  = (tid & 7) << 4;
  const int lcb  = pcb ^ ((srow & 7) << 4);
  const char* aSrc = (const char*)A  + ((size_t)(mBase + srow) * K) * 2 + lcb;
  const char* bSrc = (const char*)Bw + ((size_t)(nBase + srow) * K) * 2 + lcb;
  char* aDst = ldsA + tid * 16;
  char* bDst = ldsB + tid * 16;

  // ---- ds_read geometry (swizzled) ----
  const int fr = lane & 15;                 // fragment row
  const int kq = lane >> 4;                 // k-quad
  const int xr = (fr & 7) << 4;
  const int ofk0 = ((kq << 4))      ^ xr;   // k-step 0 colbyte
  const int ofk1 = (64 + (kq << 4)) ^ xr;   // k-step 1 colbyte
  const char* aRow = ldsA + (wr * 64 + fr) * 128;
  const char* bRow = ldsB + (wc * 32 + fr) * 128;

  f32x4 acc[4][2];
  #pragma unroll
  for (int m = 0; m < 4; ++m)
    #pragma unroll
    for (int n = 0; n < 2; ++n) acc[m][n] = f32x4{0.f, 0.f, 0.f, 0.f};

  // ---- prologue: stage tile 0, drain, barrier ----
  STAGE_A(0, 0);
  STAGE_B(0, 0);
  asm volatile("s_waitcnt vmcnt(0)" ::: "memory");
  BAR;

  for (int t = 0; t < NT; ++t) {
    const int cur  = t & 1;
    const int nxt  = cur ^ 1;
    const int toff = (t + 1) * 128;
    const char* aR = aRow + cur * 16384;
    const char* bR = bRow + cur * 16384;
    bf16x8 Af[4], Bf[2];

    // ===== phase 1: k-step 0; issue A-stage for t+1 =====
    if (t + 1 < NT) STAGE_A(toff, nxt);
    #pragma unroll
    for (int n = 0; n < 2; ++n) Bf[n] = *(const bf16x8*)(bR + n * 2048 + ofk0);
    #pragma unroll
    for (int m = 0; m < 4; ++m) Af[m] = *(const bf16x8*)(aR + m * 2048 + ofk0);
    FENCE; BAR;
    asm volatile("s_waitcnt lgkmcnt(0)" ::: "memory");
    __builtin_amdgcn_sched_barrier(0);
    __builtin_amdgcn_s_setprio(1);
    #pragma unroll
    for (int m = 0; m < 4; ++m)
      #pragma unroll
      for (int n = 0; n < 2; ++n)
        acc[m][n] = __builtin_amdgcn_mfma_f32_16x16x32_bf16(Af[m], Bf[n], acc[m][n], 0, 0, 0);
    __builtin_amdgcn_s_setprio(0);
    FENCE; BAR;

    // ===== phase 2: k-step 1; issue B-stage; drain; flip =====
    if (t + 1 < NT) STAGE_B(toff, nxt);
    #pragma unroll
    for (int n = 0; n < 2; ++n) Bf[n] = *(const bf16x8*)(bR + n * 2048 + ofk1);
    #pragma unroll
    for (int m = 0; m < 4; ++m) Af[m] = *(const bf16x8*)(aR + m * 2048 + ofk1);
    FENCE; BAR;
    asm volatile("s_waitcnt lgkmcnt(0)" ::: "memory");
    __builtin_amdgcn_sched_barrier(0);
    __builtin_amdgcn_s_setprio(1);
    #pragma unroll
    for (int m = 0; m < 4; ++m)
      #pragma unroll
      for (int n = 0; n < 2; ++n)
        acc[m][n] = __builtin_amdgcn_mfma_f32_16x16x32_bf16(Af[m], Bf[n], acc[m][n], 0, 0, 0);
    __builtin_amdgcn_s_setprio(0);
    if (t + 1 < NT) asm volatile("s_waitcnt vmcnt(0)" ::: "memory");
    FENCE; BAR;
  }

  // ---- epilogue: C/D layout col=lane&15, row=(lane>>4)*4+reg ----
  // Overlapped with the co-resident block's K-loop (2 blocks/CU).
  const int fq = lane >> 4;
  #pragma unroll
  for (int n = 0; n < 2; ++n) {
    const int col = nBase + wc * 32 + n * 16 + fr;
    const float bv = bias[col];
    #pragma unroll
    for (int m = 0; m < 4; ++m) {
      const int row0 = mBase + wr * 64 + m * 16 + fq * 4;
      #pragma unroll
      for (int r = 0; r < 4; ++r)
        C[(size_t)(row0 + r) * Nn + col] = acc[m][n][r] + bv;
    }
  }
}

extern "C" void kernel_launch(void* const* d_in, const int* in_sizes, int n_in,
                              void* d_out, int out_size, void* d_ws, size_t ws_size,
                              hipStream_t stream) {
  const float* x    = (const float*)d_in[0];
  const float* y    = (const float*)d_in[1];
  const float* W    = (const float*)d_in[2];
  const float* bias = (const float*)d_in[3];
  float* out = (float*)d_out;

  // Workspace: A (16384x1024 bf16 = 32 MB) + Wbf16 (2 MB)
  __hip_bfloat16* Abuf = (__hip_bfloat16*)d_ws;
  __hip_bfloat16* Wbuf = (__hip_bfloat16*)((char*)d_ws + (size_t)16384 * 1024 * 2);

  wcvt_kernel<<<1024, 256, 0, stream>>>(W, Wbuf);
  attn_kernel<<<4096, 256, 0, stream>>>(x, y, Abuf);
  gemm128<<<1024, 512, 0, stream>>>(Abuf, Wbuf, bias, out);
}